// Round 6
// baseline (163.134 us; speedup 1.0000x reference)
//
#include <hip/hip_runtime.h>
#include <hip/hip_bf16.h>
#include <cstddef>

// ---------------- problem constants ----------------
#define BB   8
#define HH   120
#define WW   160
#define HW   19200          // HH*WW
#define NPIX 153600         // BB*HW
#define CORC 196

#define AS_  ((float)(6.0/127.0))   // ACT_SCALE
#define FS_  0.03125f               // FLOW_SCALE = 3.96875/127 = 2^-5 exactly

// ws layout:
//   float[0]=sd, float[1]=sp, float[2]=s_c1
//   ushort[32 .. 32+21504)      : convc1 B-frags (bf16 int codes)
//   float[OFF_WF1 .. +128)      : Wf1 dequant
//   float[OFF_WF2 .. +2048)     : Wf2 dequant transposed
//   float[OFF_WD  .. +1152)     : Wd integer codes
//   ushort[OFF_WPQ_US .. +10240): Wp B-frags (bf16 int codes)
#define OFF_WF1 18832
#define OFF_WF2 18960
#define OFF_WD  21008
#define OFF_WPQ_US 44320
#define CFQ_BYTE_OFF 131072         // int8 activation buffer, 8*128*19200 bytes

typedef __attribute__((ext_vector_type(8)))  short short8;
typedef __attribute__((ext_vector_type(4)))  float f32x4;

__device__ __forceinline__ float clip127(float x) {
    return fminf(fmaxf(x, -127.f), 127.f);
}

// round-to-nearest-even fp32 -> bf16 (finite inputs only)
__device__ __forceinline__ unsigned short f2bf(float x) {
    unsigned int u = __float_as_uint(x);
    unsigned int r = (u + 0x7fffu + ((u >> 16) & 1u)) >> 16;
    return (unsigned short)r;
}

// ---------------- kernel 0: weight fake-quant ----------------
__global__ __launch_bounds__(256) void quant_weights(
    const float* __restrict__ Wc1, const float* __restrict__ Wf1,
    const float* __restrict__ Wf2, const float* __restrict__ Wd,
    const float* __restrict__ Wp,  float* __restrict__ ws)
{
    __shared__ float red[256];
    const int t = blockIdx.x;
    const float* src = (t == 0) ? Wc1 : (t == 1) ? Wf1 : (t == 2) ? Wf2 : (t == 3) ? Wd : Wp;
    const int n = (t == 0) ? 18816 : (t == 1) ? 128 : (t == 2) ? 2048 : (t == 3) ? 1152 : 10240;
    const int tid = threadIdx.x;

    float m = 0.f;
    for (int i = tid; i < n; i += 256) m = fmaxf(m, fabsf(src[i]));
    red[tid] = m;
    __syncthreads();
    for (int s = 128; s > 0; s >>= 1) {
        if (tid < s) red[tid] = fmaxf(red[tid], red[tid + s]);
        __syncthreads();
    }
    const float s = red[0] / 127.0f + 1e-12f;

    if (t == 0) {
        // convc1 weights as MFMA B-frags: o = nt*16+(l&15), k = kt*32+((l>>4)<<3)+e
        unsigned short* bf = (unsigned short*)ws + 32;
        for (int j = tid; j < 21504; j += 256) {
            const int e    = j & 7;
            const int l    = (j >> 3) & 63;
            const int tile = j >> 9;
            const int nt   = tile % 6;
            const int kt   = tile / 6;
            const int out  = nt * 16 + (l & 15);
            const int k    = kt * 32 + ((l >> 4) << 3) + e;
            float q = 0.f;
            if (k < 196) q = clip127(rintf(Wc1[out * 196 + k] / s));
            bf[j] = f2bf(q);
        }
        if (tid == 0) ws[2] = s;
    } else if (t == 4) {
        // pointwise weights as MFMA B-frags: 5 n-tiles x 4 k-steps
        unsigned short* bf = (unsigned short*)ws + OFF_WPQ_US;
        for (int j = tid; j < 10240; j += 256) {
            const int e    = j & 7;
            const int l    = (j >> 3) & 63;
            const int tile = j >> 9;     // 0..19
            const int nt   = tile % 5;
            const int kt   = tile / 5;
            const int o    = nt * 16 + (l & 15);
            const int k    = kt * 32 + ((l >> 4) << 3) + e;
            const float q  = clip127(rintf(Wp[o * 128 + k] / s));
            bf[j] = f2bf(q);
        }
        if (tid == 0) ws[1] = s;
    } else {
        for (int i = tid; i < n; i += 256) {
            const float q = clip127(rintf(src[i] / s));
            if (t == 1) {            // Wf1 [64][2]
                ws[OFF_WF1 + i] = s * q;
            } else if (t == 2) {     // Wf2 [32][64] -> transposed [64][32]
                int o = i / 64, c = i % 64;
                ws[OFF_WF2 + c * 32 + o] = s * q;
            } else {                 // Wd [128][9]: keep integer q
                ws[OFF_WD + i] = q;
            }
        }
        if (tid == 0 && t == 3) ws[0] = s;
    }
}

// ---------------- kernel 1a: convc1 (196 -> 96), MFMA + explicit SW pipeline ----
// 128 pixels/block, 4 waves; wave w owns pixels [w*32, w*32+32) as two 16-row m-tiles.
// Depth-2 prefetch of A gathers (tA/tB/tC) + depth-1 of B-frags (bA/bB) keeps ~32
// loads in flight per wave; launch_bounds(256,2) gives the 256-reg budget for it.
#define TSTRIDE 136   // t8 row stride (bytes): 34 dwords -> max 2-way LDS aliasing
__global__ __launch_bounds__(256, 2) void k1_convc1(
    const float* __restrict__ corr, const float* __restrict__ bc1,
    const float* __restrict__ ws,   signed char* __restrict__ cfq)
{
    __shared__ signed char t8[96 * TSTRIDE];   // transpose buffer [96 out][128 pix]

    const int tid = threadIdx.x;
    const int w   = tid >> 6;
    const int l   = tid & 63;
    const int p0  = blockIdx.x * 128;          // 19200 % 128 == 0 -> no batch straddle
    const int b   = p0 / HW;
    const int hw0 = p0 % HW;
    const float* cp = corr + (size_t)b * CORC * HW + hw0;

    const int r0   = w * 32 + (l & 15);        // m-tile 0 pixel row
    const int koff = (l >> 4) << 3;            // k sub-offset within 32-k step
    const short8* Bfr = (const short8*)((const unsigned short*)ws + 32);

    f32x4 a00 = {0.f,0.f,0.f,0.f}, a01 = a00, a02 = a00, a03 = a00, a04 = a00, a05 = a00;
    f32x4 a10 = a00, a11 = a00, a12 = a00, a13 = a00, a14 = a00, a15 = a00;

    float  tA[16], tB[16], tC[16];   // A prefetch buffers (constant-indexed only)
    short8 bA[6],  bB[6];            // B prefetch buffers (constant-indexed only)
    short8 h0_, l0_, h1_, l1_;

#define AISSUE(BUF, KT)                                                          \
    {   _Pragma("unroll")                                                        \
        for (int e = 0; e < 8; ++e) {                                            \
            const int c = (KT) * 32 + koff + e;                                  \
            const float* pc = cp + (size_t)c * HW;                               \
            float v0 = 0.f, v1 = 0.f;                                            \
            if ((KT) < 6 || c < CORC) { v0 = pc[r0]; v1 = pc[r0 + 16]; }         \
            BUF[e] = v0; BUF[8 + e] = v1;                                        \
        }                                                                        }

#define BLOAD(BUF, KT)                                                           \
    {   _Pragma("unroll")                                                        \
        for (int nt = 0; nt < 6; ++nt) BUF[nt] = Bfr[((KT) * 6 + nt) * 64 + l];  }

#define CONVERT(BUF)                                                             \
    {   _Pragma("unroll")                                                        \
        for (int e = 0; e < 8; ++e) {                                            \
            const float v0 = BUF[e], v1 = BUF[8 + e];                            \
            const unsigned short h0 = f2bf(v0);                                  \
            const unsigned short h1 = f2bf(v1);                                  \
            h0_[e] = (short)h0; h1_[e] = (short)h1;                              \
            l0_[e] = (short)f2bf(v0 - __uint_as_float((unsigned int)h0 << 16));  \
            l1_[e] = (short)f2bf(v1 - __uint_as_float((unsigned int)h1 << 16));  \
        }                                                                        }

#define MF(NT, A0, A1, BBUF)                                                     \
    A0 = __builtin_amdgcn_mfma_f32_16x16x32_bf16(l0_, BBUF[NT], A0, 0, 0, 0);    \
    A0 = __builtin_amdgcn_mfma_f32_16x16x32_bf16(h0_, BBUF[NT], A0, 0, 0, 0);    \
    A1 = __builtin_amdgcn_mfma_f32_16x16x32_bf16(l1_, BBUF[NT], A1, 0, 0, 0);    \
    A1 = __builtin_amdgcn_mfma_f32_16x16x32_bf16(h1_, BBUF[NT], A1, 0, 0, 0);

#define MFALL(BBUF)                                                              \
    MF(0, a00, a10, BBUF) MF(1, a01, a11, BBUF) MF(2, a02, a12, BBUF)            \
    MF(3, a03, a13, BBUF) MF(4, a04, a14, BBUF) MF(5, a05, a15, BBUF)

    // prologue: kt0,kt1 A-loads and kt0 B-frags in flight
    AISSUE(tA, 0)  BLOAD(bA, 0)  AISSUE(tB, 1)

    AISSUE(tC, 2)  BLOAD(bB, 1)  CONVERT(tA)  MFALL(bA)   // kt=0
    AISSUE(tA, 3)  BLOAD(bA, 2)  CONVERT(tB)  MFALL(bB)   // kt=1
    AISSUE(tB, 4)  BLOAD(bB, 3)  CONVERT(tC)  MFALL(bA)   // kt=2
    AISSUE(tC, 5)  BLOAD(bA, 4)  CONVERT(tA)  MFALL(bB)   // kt=3
    AISSUE(tA, 6)  BLOAD(bB, 5)  CONVERT(tB)  MFALL(bA)   // kt=4
                   BLOAD(bA, 6)  CONVERT(tC)  MFALL(bB)   // kt=5
                                 CONVERT(tA)  MFALL(bA)   // kt=6

#undef AISSUE
#undef BLOAD
#undef CONVERT
#undef MF
#undef MFALL

    // ---- epilogue: quant chain -> t8 transpose buffer ----
    const float sc1 = ws[2];

#define EPI(ACC, NT, TILE)                                                        \
    {   const int out = (NT) * 16 + (l & 15);                                     \
        const float bias = bc1[out];                                              \
        _Pragma("unroll")                                                         \
        for (int i = 0; i < 4; ++i) {                                             \
            const int prow = w * 32 + (TILE) * 16 + ((l >> 4) << 2) + i;          \
            float v  = fmaf(sc1, ACC[i], bias);                                   \
            float aq = AS_ * clip127(rintf(v / AS_));                             \
            float r  = fmaxf(aq, 0.f);                                            \
            float kk = fminf(rintf(r * 32.f), 127.f);                             \
            float cf = kk * FS_;                                                  \
            float q8 = clip127(rintf(cf / AS_));                                  \
            t8[out * TSTRIDE + prow] = (signed char)(int)q8;                      \
        }                                                                         }
    EPI(a00, 0, 0) EPI(a01, 1, 0) EPI(a02, 2, 0) EPI(a03, 3, 0) EPI(a04, 4, 0) EPI(a05, 5, 0)
    EPI(a10, 0, 1) EPI(a11, 1, 1) EPI(a12, 2, 1) EPI(a13, 3, 1) EPI(a14, 4, 1) EPI(a15, 5, 1)
#undef EPI
    __syncthreads();

    // ---- coalesced store: 96 rows x 128 bytes ----
#pragma unroll
    for (int r = 0; r < 12; ++r) {
        const int d   = r * 256 + tid;     // 3072 dwords total
        const int out = d >> 5;
        const int pd  = d & 31;
        const unsigned int v = *(const unsigned int*)(t8 + out * TSTRIDE + pd * 4);
        *(unsigned int*)(cfq + (size_t)(b * 128 + out) * HW + hw0 + pd * 4) = v;
    }
}

// ---------------- kernel 1b: flo path (convf1 2->64, convf2 64->32) ----------------
typedef __attribute__((ext_vector_type(16))) float f32x16;
__global__ __launch_bounds__(256) void k1_flo(
    const float* __restrict__ flow, const float* __restrict__ bf1,
    const float* __restrict__ bf2,  const float* __restrict__ ws,
    signed char* __restrict__ cfq)
{
    const int p  = blockIdx.x * 256 + threadIdx.x;
    const int b  = p / HW;
    const int hw = p % HW;

    const float f0 = flow[(size_t)(b * 2) * HW + hw];
    const float f1 = flow[(size_t)(b * 2 + 1) * HW + hw];

    f32x16 a2a, a2b;
#pragma unroll
    for (int j = 0; j < 16; ++j) { a2a[j] = 0.f; a2b[j] = 0.f; }

    for (int c = 0; c < 64; ++c) {
        const float w0 = ws[OFF_WF1 + 2 * c];
        const float w1 = ws[OFF_WF1 + 2 * c + 1];
        float v  = fmaf(f0, w0, fmaf(f1, w1, bf1[c]));
        float r  = fmaxf(v, 0.f);
        float af = AS_ * fminf(rintf(r / AS_), 127.f);
        const float* w2 = ws + OFF_WF2 + c * 32;
#pragma unroll
        for (int j = 0; j < 16; ++j) {
            a2a[j] = fmaf(af, w2[j],      a2a[j]);
            a2b[j] = fmaf(af, w2[16 + j], a2b[j]);
        }
    }

    signed char* op = cfq + (size_t)b * 128 * HW + (size_t)96 * HW + hw;
#define FLOEPI(ACC, BASE)                                                        \
    _Pragma("unroll")                                                            \
    for (int j = 0; j < 16; ++j) {                                               \
        const int o = (BASE) + j;                                                \
        float v  = ACC[j] + bf2[o];                                              \
        float aq = AS_ * clip127(rintf(v / AS_));                                \
        float r  = fmaxf(aq, 0.f);                                               \
        float kk = fminf(rintf(r * 32.f), 127.f);                                \
        float cf = kk * FS_;                                                     \
        float q8 = clip127(rintf(cf / AS_));                                     \
        op[(size_t)o * HW] = (signed char)(int)q8;                               \
    }
    FLOEPI(a2a, 0) FLOEPI(a2b, 16)
#undef FLOEPI
}

// ---------------- kernel 2: depthwise 3x3 (VALU, exact) + pointwise via MFMA ----------------
#define STG_STRIDE 44
__global__ __launch_bounds__(256) void k2_dwpw(
    const float* __restrict__ flow, const float* __restrict__ bd,
    const float* __restrict__ bp,   const float* __restrict__ ws,
    const signed char* __restrict__ cfq, float* __restrict__ out)
{
    __shared__ signed char stage[4 * 128 * STG_STRIDE];   // [row][c][44]
    __shared__ unsigned short afrag[64 * 136];            // [pix][136] bf16 codes

    const int tid = threadIdx.x;
    const int bid = blockIdx.x;
    const int b   = bid / 300;          // 60 row-tiles * 5 col-tiles
    const int rem = bid % 300;
    const int h0  = (rem / 5) * 2;
    const int w0  = (rem % 5) * 32;

    for (int j = tid; j < 5120; j += 256) {
        const int i   = j % 10;
        const int c   = (j / 10) % 128;
        const int row = j / 1280;
        const int h   = h0 - 1 + row;
        const int wb  = w0 - 4 + 4 * i;
        unsigned int v = 0u;
        if (h >= 0 && h < HH && wb >= 0 && wb <= WW - 4)
            v = *(const unsigned int*)(cfq + ((size_t)(b * 128 + c) * HW + (size_t)h * WW + wb));
        *(unsigned int*)(stage + (row * 128 + c) * STG_STRIDE + i * 4) = v;
    }
    __syncthreads();

    const int c0 = tid & 63;
    const int pg = tid >> 6;
    const float sd = ws[0], sp = ws[1];
    const float ASsd = AS_ * sd;

    float wd0[9], wd1[9];
#pragma unroll
    for (int t9 = 0; t9 < 9; ++t9) {
        wd0[t9] = ws[OFF_WD + c0 * 9 + t9];
        wd1[t9] = ws[OFF_WD + (c0 + 64) * 9 + t9];
    }
    const float bd0 = bd[c0], bd1 = bd[c0 + 64];

#pragma unroll
    for (int pp = 0; pp < 16; ++pp) {
        const int pix = pg * 16 + pp;
        const int r   = pix >> 5;
        const int col = pix & 31;
        float s0 = 0.f, s1 = 0.f;
#pragma unroll
        for (int dy = 0; dy < 3; ++dy) {
            const int rb = (r + dy) * 128;
            const int xb = 3 + col;
#pragma unroll
            for (int dd = 0; dd < 3; ++dd) {
                s0 = fmaf((float)stage[(rb + c0     ) * STG_STRIDE + xb + dd], wd0[dy * 3 + dd], s0);
                s1 = fmaf((float)stage[(rb + c0 + 64) * STG_STRIDE + xb + dd], wd1[dy * 3 + dd], s1);
            }
        }
        const float q0 = clip127(rintf(fmaf(ASsd, s0, bd0) / AS_));
        const float q1 = clip127(rintf(fmaf(ASsd, s1, bd1) / AS_));
        afrag[pix * 136 + c0]      = f2bf(q0);
        afrag[pix * 136 + c0 + 64] = f2bf(q1);
    }
    __syncthreads();

    const int wv = tid >> 6;
    const int l  = tid & 63;
    const unsigned short* A = afrag + (size_t)(wv * 16 + (l & 15)) * 136 + ((l >> 4) << 3);
    const short8* Bfr = (const short8*)((const unsigned short*)ws + OFF_WPQ_US);

    f32x4 pc0 = {0.f,0.f,0.f,0.f}, pc1 = pc0, pc2 = pc0, pc3 = pc0, pc4 = pc0;

#define PTSTEP(ACC, KT, NT)                                                      \
    {   short8 bq = Bfr[((KT) * 5 + (NT)) * 64 + l];                             \
        ACC = __builtin_amdgcn_mfma_f32_16x16x32_bf16(a_, bq, ACC, 0, 0, 0);     }
#pragma unroll
    for (int kt = 0; kt < 4; ++kt) {
        short8 a_ = *(const short8*)(A + kt * 32);
        PTSTEP(pc0, kt, 0) PTSTEP(pc1, kt, 1) PTSTEP(pc2, kt, 2)
        PTSTEP(pc3, kt, 3) PTSTEP(pc4, kt, 4)
    }
#undef PTSTEP

    const float ASsp = AS_ * sp;
    float* ob = out + (size_t)b * 82 * HW;

#define PEPI(ACC, NT)                                                            \
    {   const int o = (NT) * 16 + (l & 15);                                      \
        const float bias = bp[o];                                                \
        _Pragma("unroll")                                                        \
        for (int i = 0; i < 4; ++i) {                                            \
            const int pix = wv * 16 + ((l >> 4) << 2) + i;                       \
            const int hw  = (h0 + (pix >> 5)) * WW + w0 + (pix & 31);            \
            float v = fmaf(ASsp, ACC[i], bias);                                  \
            float r = fmaxf(v, 0.f);                                             \
            float k = fminf(rintf(r * 32.f), 127.f);                             \
            ob[(size_t)o * HW + hw] = k * FS_;                                   \
        }                                                                        }
    PEPI(pc0, 0) PEPI(pc1, 1) PEPI(pc2, 2) PEPI(pc3, 3) PEPI(pc4, 4)
#undef PEPI

    if (tid < 128) {
        const int ch  = tid >> 6;
        const int pix = tid & 63;
        const int hw  = (h0 + (pix >> 5)) * WW + w0 + (pix & 31);
        const float f = flow[(size_t)(b * 2 + ch) * HW + hw];
        const float k = clip127(rintf(f * 32.f));
        ob[(size_t)(80 + ch) * HW + hw] = k * FS_;
    }
}

// ---------------- launcher ----------------
extern "C" void kernel_launch(void* const* d_in, const int* in_sizes, int n_in,
                              void* d_out, int out_size, void* d_ws, size_t ws_size,
                              hipStream_t stream) {
    const float* flow = (const float*)d_in[0];
    const float* corr = (const float*)d_in[1];
    const float* Wc1  = (const float*)d_in[2];
    const float* bc1  = (const float*)d_in[3];
    const float* Wf1  = (const float*)d_in[4];
    const float* bf1  = (const float*)d_in[5];
    const float* Wf2  = (const float*)d_in[6];
    const float* bf2  = (const float*)d_in[7];
    const float* Wd   = (const float*)d_in[8];
    const float* bd   = (const float*)d_in[9];
    const float* Wp   = (const float*)d_in[10];
    const float* bp   = (const float*)d_in[11];

    float* ws = (float*)d_ws;
    signed char* cfq = (signed char*)d_ws + CFQ_BYTE_OFF;
    float* out = (float*)d_out;

    quant_weights<<<5, 256, 0, stream>>>(Wc1, Wf1, Wf2, Wd, Wp, ws);
    k1_convc1<<<NPIX / 128, 256, 0, stream>>>(corr, bc1, ws, cfq);
    k1_flo<<<NPIX / 256, 256, 0, stream>>>(flow, bf1, bf2, ws, cfq);
    k2_dwpw<<<2400, 256, 0, stream>>>(flow, bd, bp, ws, cfq, out);
}